// Round 1
// baseline (5164.724 us; speedup 1.0000x reference)
//
#include <hip/hip_runtime.h>
#include <hip/hip_cooperative_groups.h>

namespace cg = cooperative_groups;

#define T_STEPS 512
#define BSZ 64
#define DIM 512
#define HID 512
#define NGATE 2048
#define NWG 64
#define NTHR 512

typedef __attribute__((ext_vector_type(4))) float f32x4;
typedef __attribute__((ext_vector_type(8))) short short8;

__device__ __forceinline__ unsigned short f2bf(float f) {
  unsigned int u = __float_as_uint(f);
  u += 0x7FFF + ((u >> 16) & 1);   // RNE
  return (unsigned short)(u >> 16);
}

__device__ __forceinline__ float sigm_f(float x) { return 1.0f / (1.0f + __expf(-x)); }
__device__ __forceinline__ float tanh_f(float x) { return 2.0f / (1.0f + __expf(-2.0f * x)) - 1.0f; }

__global__ __launch_bounds__(NTHR, 1) void lstm_kernel(
    const float* __restrict__ X, const float* __restrict__ W,
    const float* __restrict__ Bv, float* __restrict__ Out,
    unsigned int* __restrict__ flags)
{
  extern __shared__ char lds[];
  char* Wl = lds;            // [32 cols][1024 k] bf16, XOR-swizzled : 65536 B
  char* Cb = lds + 65536;    // [64 b][512 k]   bf16, XOR-swizzled : 65536 B

  const int tid  = threadIdx.x;
  const int wg   = blockIdx.x;   // 0..63
  const int lane = tid & 63;
  const int wv   = tid >> 6;     // 0..7
  const int m    = wv & 3;       // M-tile: batches [16m,16m+16)
  const int ng   = wv >> 2;      // N-half: cols [16ng,16ng+16) of this WG's 32

  // ---- one-time: W slice (cols = {f,i,g,o} x 8 h-cols of this WG) -> LDS bf16 ----
  {
    const int n32  = tid & 31;          // packed col: gate = (n32&15)>>2, hl = n32&3, half = n32>>4
    const int kc   = tid >> 5;          // 0..15 k-chunks of 64
    const int g    = (n32 & 15) >> 2;
    const int gcol = g * 512 + wg * 8 + (n32 >> 4) * 4 + (n32 & 3);
    const int xorv = (n32 & 7) << 4;
    for (int c8 = 0; c8 < 8; ++c8) {
      const int k0 = kc * 64 + c8 * 8;
      short8 v;
      #pragma unroll
      for (int j = 0; j < 8; ++j)
        v[j] = (short)f2bf(W[(size_t)(k0 + j) * NGATE + gcol]);
      *(short8*)(Wl + ((n32 * 2048 + k0 * 2) ^ xorv)) = v;
    }
  }

  // ---- stage a [64][512] fp32 matrix -> comb LDS as bf16 (swizzled) ----
  auto stage = [&](const float* __restrict__ src) {
    #pragma unroll
    for (int s = 0; s < 8; ++s) {
      const int flat = s * 4096 + tid * 8;
      const float4 v0 = *(const float4*)(src + flat);
      const float4 v1 = *(const float4*)(src + flat + 4);
      short8 v;
      v[0] = (short)f2bf(v0.x); v[1] = (short)f2bf(v0.y);
      v[2] = (short)f2bf(v0.z); v[3] = (short)f2bf(v0.w);
      v[4] = (short)f2bf(v1.x); v[5] = (short)f2bf(v1.y);
      v[6] = (short)f2bf(v1.z); v[7] = (short)f2bf(v1.w);
      const int b  = flat >> 9;
      const int k0 = flat & 511;
      *(short8*)(Cb + ((b * 1024 + k0 * 2) ^ ((b & 7) << 4))) = v;
    }
  };

  // ---- MFMA fragment addressing (16x16x32 bf16) ----
  // A frag: lane holds row (lane&15), k = (lane>>4)*8 + j   (8 consecutive bf16)
  // B frag: lane holds col (lane&15), same k grouping
  const int arow  = m * 16 + (lane & 15);
  const int n32f  = ng * 16 + (lane & 15);
  const int kgrp  = (lane >> 4) << 3;
  const int abase = arow * 1024 + kgrp * 2;
  const int axor  = (arow & 7) << 4;
  const int bbase = n32f * 2048 + kgrp * 2;
  const int bxor  = (n32f & 7) << 4;

  auto mfma_pass = [&](int pass, f32x4& acc) {
    const int bofs = bbase + pass * 1024;   // pass 0: W rows [0,512) (x), pass 1: [512,1024) (h)
    #pragma unroll
    for (int kk = 0; kk < 16; ++kk) {
      short8 a = *(const short8*)(Cb + ((abase + kk * 64) ^ axor));
      short8 b = *(const short8*)(Wl + ((bofs  + kk * 64) ^ bxor));
      acc = __builtin_amdgcn_mfma_f32_16x16x32_bf16(a, b, acc, 0, 0, 0);
    }
  };

  // ---- epilogue constants: lane's col = gate*4 + hl ----
  const int n16 = lane & 15;
  const int gp  = n16 >> 2;                    // 0=f 1=i 2=g 3=o
  const int hc  = wg * 8 + ng * 4 + (n16 & 3); // global h column
  const float bias = Bv[gp * 512 + hc];

  // ---- bootstrap: zero flags, then grid-wide sync (robust across graph replays) ----
  if (tid == 0)
    __hip_atomic_store(&flags[wg], 0u, __ATOMIC_RELAXED, __HIP_MEMORY_SCOPE_AGENT);
  cg::this_grid().sync();

  float cst[4] = {0.f, 0.f, 0.f, 0.f};   // c state (valid on f-lanes)

  for (int t = 0; t < T_STEPS; ++t) {
    f32x4 acc = {0.f, 0.f, 0.f, 0.f};

    // x-part first: overlaps with other WGs still finishing step t-1
    stage(X + (size_t)t * (BSZ * DIM));
    __syncthreads();
    mfma_pass(0, acc);

    if (t > 0) {
      if (tid < NWG) {
        while (__hip_atomic_load(&flags[tid], __ATOMIC_RELAXED,
                                 __HIP_MEMORY_SCOPE_AGENT) < (unsigned)t) {}
      }
      __syncthreads();
      if (tid == 0) __threadfence();   // acquire side: buffer_inv -> no stale L2 lines
      __syncthreads();
      stage(Out + (size_t)(t - 1) * (BSZ * HID));  // h_{t-1} (fresh from LLC)
      __syncthreads();
      mfma_pass(1, acc);
    }

    // ---- pointwise: lane gp holds one gate for (4 rows, col hc) ----
    float av[4], tn[4], vi[4], vg[4];
    #pragma unroll
    for (int r = 0; r < 4; ++r) {
      const float pre = acc[r] + bias;
      av[r] = (gp == 2) ? tanh_f(pre) : sigm_f(pre);
    }
    #pragma unroll
    for (int r = 0; r < 4; ++r) vi[r] = __shfl_xor(av[r], 4);   // f-lane <- i
    #pragma unroll
    for (int r = 0; r < 4; ++r) vg[r] = __shfl_xor(av[r], 8);   // f-lane <- g
    #pragma unroll
    for (int r = 0; r < 4; ++r) {
      const float cn = av[r] * cst[r] + vi[r] * vg[r];          // valid on f-lanes
      if (gp == 0) cst[r] = cn;
      tn[r] = tanh_f(cn);
    }
    #pragma unroll
    for (int r = 0; r < 4; ++r) tn[r] = __shfl_xor(tn[r], 12);  // o-lane <- tanh(c)

    if (gp == 3) {
      #pragma unroll
      for (int r = 0; r < 4; ++r) {
        const int brow = m * 16 + ((lane >> 4) << 2) + r;
        const float h = av[r] * tn[r];
        // agent-scope store: bypasses L2 so the flag makes it visible cross-XCD
        __hip_atomic_store(Out + ((size_t)t * BSZ + brow) * HID + hc, h,
                           __ATOMIC_RELAXED, __HIP_MEMORY_SCOPE_AGENT);
        if (t == T_STEPS - 1)
          Out[(size_t)T_STEPS * BSZ * HID + (size_t)brow * HID + hc] = h;   // hx
      }
    }
    if (gp == 0 && t == T_STEPS - 1) {
      #pragma unroll
      for (int r = 0; r < 4; ++r) {
        const int brow = m * 16 + ((lane >> 4) << 2) + r;
        Out[(size_t)T_STEPS * BSZ * HID + BSZ * HID + (size_t)brow * HID + hc] = cst[r]; // cx
      }
    }

    __syncthreads();   // drains all waves' h stores (vmcnt) before publishing
    if (tid == 0)
      __hip_atomic_store(&flags[wg], (unsigned)(t + 1),
                         __ATOMIC_RELEASE, __HIP_MEMORY_SCOPE_AGENT);
  }
}

extern "C" void kernel_launch(void* const* d_in, const int* in_sizes, int n_in,
                              void* d_out, int out_size, void* d_ws, size_t ws_size,
                              hipStream_t stream) {
  const float* X  = (const float*)d_in[0];
  const float* W  = (const float*)d_in[1];
  const float* Bv = (const float*)d_in[2];
  float* Out = (float*)d_out;
  unsigned int* flags = (unsigned int*)d_ws;

  hipFuncSetAttribute((const void*)lstm_kernel,
                      hipFuncAttributeMaxDynamicSharedMemorySize, 131072);

  void* args[5];
  args[0] = (void*)&X;
  args[1] = (void*)&W;
  args[2] = (void*)&Bv;
  args[3] = (void*)&Out;
  args[4] = (void*)&flags;
  hipLaunchCooperativeKernel((const void*)lstm_kernel, dim3(NWG), dim3(NTHR),
                             args, 131072, stream);
}